// Round 4
// baseline (90.042 us; speedup 1.0000x reference)
//
#include <hip/hip_runtime.h>
#include <hip/hip_bf16.h>
#include <stdint.h>

#define HID 128

typedef __attribute__((ext_vector_type(8))) __bf16 bf16x8;
typedef __attribute__((ext_vector_type(4))) float floatx4;

// pack two fp32 -> one dword of two bf16 (round-to-nearest-even), 5 VALU ops
__device__ inline unsigned int pack2_bf16_rn(float lo, float hi) {
    unsigned int ulo = __float_as_uint(lo);
    unsigned int uhi = __float_as_uint(hi);
    unsigned int rlo = ulo + 0x7FFFu + ((ulo >> 16) & 1u);
    unsigned int rhi = uhi + 0x7FFFu + ((uhi >> 16) & 1u);
    // result bytes [1:0] = rlo bytes [3:2], bytes [3:2] = rhi bytes [3:2]
    return __builtin_amdgcn_perm(rhi, rlo, 0x07060302);
}

// load 8 consecutive fp32, convert to bf16x8 fragment entirely in registers
__device__ inline bf16x8 load_cvt8(const float* __restrict__ p) {
    float4 v0 = *(const float4*)(p);
    float4 v1 = *(const float4*)(p + 4);
    uint4 u;
    u.x = pack2_bf16_rn(v0.x, v0.y);
    u.y = pack2_bf16_rn(v0.z, v0.w);
    u.z = pack2_bf16_rn(v1.x, v1.y);
    u.w = pack2_bf16_rn(v1.z, v1.w);
    return __builtin_bit_cast(bf16x8, u);
}

// One wave owns a 16-row x 16-col output tile. No LDS, no barriers.
// 8192 waves total -> 8 waves/SIMD across 256 CUs.
__global__ __launch_bounds__(256, 8) void elem_update_kernel(
    const float* __restrict__ h_prev,
    const float* __restrict__ m_curr,
    const int* __restrict__ atom_types,
    const float* __restrict__ weight,
    float* __restrict__ out)
{
    const int tid  = threadIdx.x;
    const int lane = tid & 63;
    const int wave = tid >> 6;
    const int l15  = lane & 15;
    const int quad = lane >> 4;

    const int wg       = blockIdx.x * 4 + wave;  // global wave id
    const int row_tile = wg >> 3;                // 16-row tile index
    const int co       = wg & 7;                 // column octant (16 cols)
    const int r0       = row_tile * 16;
    const int c0       = co * 16;

    // species of this wave's 16 rows (replicated across quads)
    const int t = atom_types[r0 + l15];

    int s = 0;
    while (s < 16) {
        const int z = __shfl(t, s);                       // wave-uniform species
        unsigned long long neq = __ballot(t != z);
        unsigned bits = (unsigned)(neq & 0xFFFFull) & ~((1u << (s + 1)) - 1u);
        const int e = bits ? (int)__builtin_ctz(bits) : 16;   // segment [s,e)

        const float* __restrict__ Wz = weight + (size_t)z * HID * HID;

        // C-init = h_prev at D-layout positions: row=quad*4+r, col=c0+l15
        floatx4 acc;
        #pragma unroll
        for (int r = 0; r < 4; ++r) {
            acc[r] = h_prev[(size_t)(r0 + quad * 4 + r) * HID + c0 + l15];
        }

        #pragma unroll
        for (int kk = 0; kk < 4; ++kk) {
            // A-frag: A[m=l15][k=kk*32+quad*8+j] = m_curr row (r0+l15)
            bf16x8 a = load_cvt8(m_curr + (size_t)(r0 + l15) * HID + kk * 32 + quad * 8);
            // B-frag: B[k][n=l15] = W[n][k] -> W row (c0+l15)
            bf16x8 b = load_cvt8(Wz + (size_t)(c0 + l15) * HID + kk * 32 + quad * 8);
            acc = __builtin_amdgcn_mfma_f32_16x16x32_bf16(a, b, acc, 0, 0, 0);
        }

        // epilogue: D[row=quad*4+r][col=c0+l15], only rows in [s,e)
        #pragma unroll
        for (int r = 0; r < 4; ++r) {
            int row = quad * 4 + r;
            if (row >= s && row < e) {
                size_t idx = (size_t)(r0 + row) * HID + c0 + l15;
                out[idx] = acc[r];
            }
        }
        s = e;
    }
}

extern "C" void kernel_launch(void* const* d_in, const int* in_sizes, int n_in,
                              void* d_out, int out_size, void* d_ws, size_t ws_size,
                              hipStream_t stream) {
    const float* h_prev     = (const float*)d_in[0];
    const float* m_curr     = (const float*)d_in[1];
    const int*   atom_types = (const int*)d_in[2];
    const float* weight     = (const float*)d_in[3];
    float*       out        = (float*)d_out;

    const int n_nodes = in_sizes[2];            // 16384
    const int blocks  = (n_nodes / 16) * 8 / 4; // 2048 blocks x 4 waves = 8192 waves
    elem_update_kernel<<<blocks, 256, 0, stream>>>(h_prev, m_curr, atom_types, weight, out);
}

// Round 5
// 89.520 us; speedup vs baseline: 1.0058x; 1.0058x over previous
//
#include <hip/hip_runtime.h>
#include <hip/hip_bf16.h>
#include <stdint.h>

#define HID 128

typedef __attribute__((ext_vector_type(8))) __bf16 bf16x8;
typedef __attribute__((ext_vector_type(4))) float floatx4;

// pack two fp32 -> one dword of two bf16 (round-to-nearest-even)
__device__ inline unsigned int pack2_bf16_rn(float lo, float hi) {
    unsigned int ulo = __float_as_uint(lo);
    unsigned int uhi = __float_as_uint(hi);
    unsigned int rlo = ulo + 0x7FFFu + ((ulo >> 16) & 1u);
    unsigned int rhi = uhi + 0x7FFFu + ((uhi >> 16) & 1u);
    return __builtin_amdgcn_perm(rhi, rlo, 0x07060302); // [hi.b3 hi.b2 lo.b3 lo.b2]
}

// load 8 consecutive fp32, convert to bf16x8 fragment in registers
__device__ inline bf16x8 load_cvt8(const float* __restrict__ p) {
    float4 v0 = *(const float4*)(p);
    float4 v1 = *(const float4*)(p + 4);
    uint4 u;
    u.x = pack2_bf16_rn(v0.x, v0.y);
    u.y = pack2_bf16_rn(v0.z, v0.w);
    u.z = pack2_bf16_rn(v1.x, v1.y);
    u.w = pack2_bf16_rn(v1.z, v1.w);
    return __builtin_bit_cast(bf16x8, u);
}

// One wave owns a 16-row x 32-col output tile. No LDS, no barriers.
// 4096 waves -> 16 waves/CU at 4 waves/SIMD (128-VGPR budget).
__global__ __launch_bounds__(256, 4) void elem_update_kernel(
    const float* __restrict__ h_prev,
    const float* __restrict__ m_curr,
    const int* __restrict__ atom_types,
    const float* __restrict__ weight,
    float* __restrict__ out)
{
    const int tid  = threadIdx.x;
    const int lane = tid & 63;
    const int wave = tid >> 6;
    const int l15  = lane & 15;
    const int quad = lane >> 4;

    const int wg       = blockIdx.x * 4 + wave;
    const int row_tile = wg >> 2;                // 16-row tile
    const int cq       = wg & 3;                 // 32-col quarter
    const int r0       = row_tile * 16;
    const int c0       = cq * 32;

    const int t  = atom_types[r0 + l15];         // species of my 16 rows
    const int z0 = __shfl(t, 0);
    const unsigned long long diff = __ballot(t != z0) & 0xFFFFull;

    // h_prev at D-layout positions (touch-once: non-temporal), used in epilogue
    float hv[2][4];
    #pragma unroll
    for (int nt = 0; nt < 2; ++nt)
        #pragma unroll
        for (int r = 0; r < 4; ++r)
            hv[nt][r] = __builtin_nontemporal_load(
                h_prev + (size_t)(r0 + quad * 4 + r) * HID + c0 + nt * 16 + l15);

    if (diff == 0) {
        // ---- fast path: whole tile is one species (~89% of tiles) ----
        const float* __restrict__ Wz = weight + (size_t)z0 * HID * HID;
        floatx4 acc[2] = {(floatx4)(0.0f), (floatx4)(0.0f)};

        #pragma unroll
        for (int kk = 0; kk < 4; ++kk) {
            bf16x8 a = load_cvt8(m_curr + (size_t)(r0 + l15) * HID + kk * 32 + quad * 8);
            #pragma unroll
            for (int nt = 0; nt < 2; ++nt) {
                bf16x8 b = load_cvt8(Wz + (size_t)(c0 + nt * 16 + l15) * HID + kk * 32 + quad * 8);
                acc[nt] = __builtin_amdgcn_mfma_f32_16x16x32_bf16(a, b, acc[nt], 0, 0, 0);
            }
        }

        #pragma unroll
        for (int nt = 0; nt < 2; ++nt)
            #pragma unroll
            for (int r = 0; r < 4; ++r)
                __builtin_nontemporal_store(
                    hv[nt][r] + acc[nt][r],
                    out + (size_t)(r0 + quad * 4 + r) * HID + c0 + nt * 16 + l15);
    } else {
        // ---- slow path: segment loop over species boundaries ----
        int s = 0;
        while (s < 16) {
            const int z = __shfl(t, s);
            unsigned long long neq = __ballot(t != z);
            unsigned bits = (unsigned)(neq & 0xFFFFull) & ~((1u << (s + 1)) - 1u);
            const int e = bits ? (int)__builtin_ctz(bits) : 16;

            const float* __restrict__ Wz = weight + (size_t)z * HID * HID;
            floatx4 acc[2] = {(floatx4)(0.0f), (floatx4)(0.0f)};

            #pragma unroll
            for (int kk = 0; kk < 4; ++kk) {
                bf16x8 a = load_cvt8(m_curr + (size_t)(r0 + l15) * HID + kk * 32 + quad * 8);
                #pragma unroll
                for (int nt = 0; nt < 2; ++nt) {
                    bf16x8 b = load_cvt8(Wz + (size_t)(c0 + nt * 16 + l15) * HID + kk * 32 + quad * 8);
                    acc[nt] = __builtin_amdgcn_mfma_f32_16x16x32_bf16(a, b, acc[nt], 0, 0, 0);
                }
            }

            #pragma unroll
            for (int nt = 0; nt < 2; ++nt) {
                #pragma unroll
                for (int r = 0; r < 4; ++r) {
                    int row = quad * 4 + r;
                    if (row >= s && row < e)
                        __builtin_nontemporal_store(
                            hv[nt][r] + acc[nt][r],
                            out + (size_t)(r0 + row) * HID + c0 + nt * 16 + l15);
                }
            }
            s = e;
        }
    }
}

extern "C" void kernel_launch(void* const* d_in, const int* in_sizes, int n_in,
                              void* d_out, int out_size, void* d_ws, size_t ws_size,
                              hipStream_t stream) {
    const float* h_prev     = (const float*)d_in[0];
    const float* m_curr     = (const float*)d_in[1];
    const int*   atom_types = (const int*)d_in[2];
    const float* weight     = (const float*)d_in[3];
    float*       out        = (float*)d_out;

    const int n_nodes = in_sizes[2];       // 16384
    const int blocks  = n_nodes / 16;      // 1024 blocks x 4 waves = 4096 waves
    elem_update_kernel<<<blocks, 256, 0, stream>>>(h_prev, m_curr, atom_types, weight, out);
}